// Round 1
// baseline (858.541 us; speedup 1.0000x reference)
//
#include <hip/hip_runtime.h>
#include <math.h>

#define NS 8192
#define DS 64
#define HD 4096

// tanh(x) = 1 - 2/(1 + e^(2x));  e^(2x) = 2^(x * 2*log2(e))
__device__ __forceinline__ float fast_tanh(float x) {
    float t = __builtin_amdgcn_exp2f(x * 2.885390081777927f);
    float r = __builtin_amdgcn_rcpf(t + 1.0f);
    return __builtin_fmaf(-2.0f, r, 1.0f);
}

__device__ __forceinline__ float wave_sum64(float v) {
    v += __shfl_xor(v, 32, 64);
    v += __shfl_xor(v, 16, 64);
    v += __shfl_xor(v, 8, 64);
    v += __shfl_xor(v, 4, 64);
    v += __shfl_xor(v, 2, 64);
    v += __shfl_xor(v, 1, 64);
    return v;
}

__global__ __launch_bounds__(256) void qnade_kernel(
    const float* __restrict__ x, const float* __restrict__ W1,
    const float* __restrict__ b1, const float* __restrict__ W2,
    const float* __restrict__ b2, float* __restrict__ out)
{
    // W2 deinterleaved in LDS: 2 x 16 KB, read as stride-16B ds_read_b128 (conflict-free)
    __shared__ __align__(16) float w20s[HD];
    __shared__ __align__(16) float w21s[HD];

    const int tid = threadIdx.x;
    for (int i = tid; i < HD; i += 256) {
        float2 w = ((const float2*)W2)[i];
        w20s[i] = w.x;
        w21s[i] = w.y;
    }

    const int lane = tid & 63;
    const int wv   = tid >> 6;
    const int n    = (blockIdx.x << 2) + wv;   // one wave = one sample

    const float b20 = b2[0];
    const float b21 = b2[1];
    // D == 64 == wave width: lane l holds spin x[n,l]; broadcast per step via shfl
    const float xv = x[n * DS + lane];

    // lane l owns hidden indices j = 256*q + 4*l + c  (c=0..3, q=0..15)
    float4 a[16];
    const float4* b1v = (const float4*)b1;
    #pragma unroll
    for (int q = 0; q < 16; ++q) a[q] = b1v[q * 64 + lane];

    __syncthreads();

    const float4* w20v = (const float4*)w20s;
    const float4* w21v = (const float4*)w21s;

    float wav = 1.0f;
    for (int d = 0; d < DS; ++d) {
        const float xd = __shfl(xv, d, 64);
        const float4* w1v = (const float4*)(W1 + d * HD);
        float dot0 = 0.0f, dot1 = 0.0f;
        #pragma unroll
        for (int q = 0; q < 16; ++q) {
            float4 w1 = w1v[q * 64 + lane];   // coalesced 16B/lane, L1/L2-resident
            float4 av = a[q];
            float h0 = fast_tanh(av.x);
            float h1 = fast_tanh(av.y);
            float h2 = fast_tanh(av.z);
            float h3 = fast_tanh(av.w);
            float4 c0 = w20v[q * 64 + lane];
            float4 c1 = w21v[q * 64 + lane];
            dot0 = fmaf(h0, c0.x, dot0);
            dot0 = fmaf(h1, c0.y, dot0);
            dot0 = fmaf(h2, c0.z, dot0);
            dot0 = fmaf(h3, c0.w, dot0);
            dot1 = fmaf(h0, c1.x, dot1);
            dot1 = fmaf(h1, c1.y, dot1);
            dot1 = fmaf(h2, c1.z, dot1);
            dot1 = fmaf(h3, c1.w, dot1);
            // rank-1 update AFTER using a (mask is sites < d)
            av.x = fmaf(xd, w1.x, av.x);
            av.y = fmaf(xd, w1.y, av.y);
            av.z = fmaf(xd, w1.z, av.z);
            av.w = fmaf(xd, w1.w, av.w);
            a[q] = av;
        }
        dot0 = wave_sum64(dot0);
        dot1 = wave_sum64(dot1);
        float o0 = fast_tanh(dot0 + b20);
        float o1 = fast_tanh(dot1 + b21);
        float nrm = sqrtf(fmaf(o0, o0, o1 * o1));
        nrm = fmaxf(nrm, 1e-12f);
        float sel = (xd > 0.0f) ? o0 : o1;
        wav *= sel / nrm;
    }
    out[n] = wav;
}

extern "C" void kernel_launch(void* const* d_in, const int* in_sizes, int n_in,
                              void* d_out, int out_size, void* d_ws, size_t ws_size,
                              hipStream_t stream) {
    const float* x  = (const float*)d_in[0];
    const float* W1 = (const float*)d_in[1];
    const float* b1 = (const float*)d_in[2];
    const float* W2 = (const float*)d_in[3];
    const float* b2 = (const float*)d_in[4];
    float* out = (float*)d_out;

    dim3 grid(NS / 4), block(256);
    hipLaunchKernelGGL(qnade_kernel, grid, block, 0, stream, x, W1, b1, W2, b2, out);
}

// Round 2
// 447.088 us; speedup vs baseline: 1.9203x; 1.9203x over previous
//
#include <hip/hip_runtime.h>
#include <math.h>

#define NS 8192
#define DS 64
#define HD 4096
#define C2L 2.8853900817779268f   // 2*log2(e)

// tanh(x) = 1 - 2/(1 + e^(2x))
__device__ __forceinline__ float fast_tanh(float x) {
    float t = __builtin_amdgcn_exp2f(x * C2L);
    float r = __builtin_amdgcn_rcpf(t + 1.0f);
    return __builtin_fmaf(-2.0f, r, 1.0f);
}

// ---- setup: E+/E- = e^{+-2*W1}, and C01 = colsum(W2) + b2 ----
__global__ __launch_bounds__(256) void qnade_prep_E(
    const float* __restrict__ W1, float* __restrict__ Ep, float* __restrict__ Em)
{
    int i = blockIdx.x * 256 + threadIdx.x;      // 0 .. DS*HD-1
    float w = W1[i] * C2L;
    Ep[i] = __builtin_amdgcn_exp2f(w);
    Em[i] = __builtin_amdgcn_exp2f(-w);
}

__global__ __launch_bounds__(256) void qnade_prep_S(
    const float* __restrict__ W2, const float* __restrict__ b2, float* __restrict__ C01)
{
    __shared__ float p0[4], p1[4];
    int tid = threadIdx.x;
    float s0 = 0.0f, s1 = 0.0f;
    for (int h = tid; h < HD; h += 256) {
        float2 w = ((const float2*)W2)[h];
        s0 += w.x; s1 += w.y;
    }
    #pragma unroll
    for (int m = 1; m < 64; m <<= 1) {
        s0 += __shfl_xor(s0, m, 64);
        s1 += __shfl_xor(s1, m, 64);
    }
    if ((tid & 63) == 0) { p0[tid >> 6] = s0; p1[tid >> 6] = s1; }
    __syncthreads();
    if (tid == 0) {
        C01[0] = p0[0] + p0[1] + p0[2] + p0[3] + b2[0];
        C01[1] = p1[0] + p1[1] + p1[2] + p1[3] + b2[1];
    }
}

// ---- main: one block = one sample; 4 waves x 1024 hidden each ----
// state t = e^{2a}; recurrence t *= E[d]; h = 1-2r, r = 1/(1+t);
// dot = C01 - 2 * sum(r * w2)  (folded, h never materialized)
__global__ __launch_bounds__(256) void qnade_main(
    const float* __restrict__ x, const float* __restrict__ b1,
    const float* __restrict__ W2, const float* __restrict__ Ep,
    const float* __restrict__ Em, const float* __restrict__ C01,
    float* __restrict__ out)
{
    __shared__ float parts[DS * 64];   // 16 KB: [d][wv*16 + (0..7 dot0 | 8..15 dot1)]

    const int tid  = threadIdx.x;
    const int lane = tid & 63;
    const int wv   = tid >> 6;
    const int n    = blockIdx.x;
    const int hbase = wv * 1024 + lane * 4;      // + q*256 + c, q=0..3, c=0..3

    // W2 columns for my 16 hidden elements (deinterleaved into registers)
    float w20[16], w21[16];
    #pragma unroll
    for (int q = 0; q < 4; ++q) {
        const float4* p = (const float4*)(W2 + 2 * (hbase + q * 256));
        float4 A = p[0], B = p[1];
        w20[q*4+0] = A.x; w21[q*4+0] = A.y;
        w20[q*4+1] = A.z; w21[q*4+1] = A.w;
        w20[q*4+2] = B.x; w21[q*4+2] = B.y;
        w20[q*4+3] = B.z; w21[q*4+3] = B.w;
    }

    // t0 = e^{2*b1}
    float t[16];
    #pragma unroll
    for (int q = 0; q < 4; ++q) {
        float4 b = *(const float4*)(b1 + hbase + q * 256);
        t[q*4+0] = __builtin_amdgcn_exp2f(b.x * C2L);
        t[q*4+1] = __builtin_amdgcn_exp2f(b.y * C2L);
        t[q*4+2] = __builtin_amdgcn_exp2f(b.z * C2L);
        t[q*4+3] = __builtin_amdgcn_exp2f(b.w * C2L);
    }

    const float xv = x[n * DS + lane];

    for (int d = 0; d < DS; ++d) {
        float xd = __shfl(xv, d, 64);
        const float* E = (__builtin_amdgcn_readfirstlane(xd > 0.0f ? 1 : 0) ? Ep : Em)
                         + d * HD + hbase;
        float acc0 = 0.0f, acc1 = 0.0f;
        #pragma unroll
        for (int q = 0; q < 4; ++q) {
            float4 e = *(const float4*)(E + q * 256);
            #pragma unroll
            for (int c = 0; c < 4; ++c) {
                const int j = q * 4 + c;
                float tv = t[j];
                float r  = __builtin_amdgcn_rcpf(1.0f + tv);
                acc0 = __builtin_fmaf(r, w20[j], acc0);
                acc1 = __builtin_fmaf(r, w21[j], acc1);
                float ec = (c == 0) ? e.x : (c == 1) ? e.y : (c == 2) ? e.z : e.w;
                t[j] = tv * ec;             // site d becomes visible for step d+1
            }
        }
        // 3-level butterfly: lanes 0..7 end holding the 8 mod-8 class sums
        acc0 += __shfl_xor(acc0, 8, 64);
        acc0 += __shfl_xor(acc0, 16, 64);
        acc0 += __shfl_xor(acc0, 32, 64);
        acc1 += __shfl_xor(acc1, 8, 64);
        acc1 += __shfl_xor(acc1, 16, 64);
        acc1 += __shfl_xor(acc1, 32, 64);
        if (lane < 8) {
            parts[d * 64 + wv * 16 + lane]     = acc0;
            parts[d * 64 + wv * 16 + 8 + lane] = acc1;
        }
    }

    __syncthreads();

    // deferred epilogue: wave 0, lane d handles step d
    if (tid < DS) {
        const int d = tid;
        const float* p = parts + d * 64;
        float s0 = 0.0f, s1 = 0.0f;
        #pragma unroll
        for (int w = 0; w < 4; ++w) {
            #pragma unroll
            for (int i = 0; i < 8; ++i) {
                s0 += p[w * 16 + i];
                s1 += p[w * 16 + 8 + i];
            }
        }
        float dot0 = __builtin_fmaf(-2.0f, s0, C01[0]);
        float dot1 = __builtin_fmaf(-2.0f, s1, C01[1]);
        float o0 = fast_tanh(dot0);
        float o1 = fast_tanh(dot1);
        float nrm = sqrtf(__builtin_fmaf(o0, o0, o1 * o1));
        nrm = fmaxf(nrm, 1e-12f);
        float sel = (x[n * DS + d] > 0.0f) ? o0 : o1;
        float v = sel * __builtin_amdgcn_rcpf(nrm);
        v *= __shfl_xor(v, 1, 64);
        v *= __shfl_xor(v, 2, 64);
        v *= __shfl_xor(v, 4, 64);
        v *= __shfl_xor(v, 8, 64);
        v *= __shfl_xor(v, 16, 64);
        v *= __shfl_xor(v, 32, 64);
        if (tid == 0) out[n] = v;
    }
}

// ---- fallback (round-1 kernel) if ws is too small for the E tables ----
__global__ __launch_bounds__(256) void qnade_fallback(
    const float* __restrict__ x, const float* __restrict__ W1,
    const float* __restrict__ b1, const float* __restrict__ W2,
    const float* __restrict__ b2, float* __restrict__ out)
{
    __shared__ __align__(16) float w20s[HD];
    __shared__ __align__(16) float w21s[HD];
    const int tid = threadIdx.x;
    for (int i = tid; i < HD; i += 256) {
        float2 w = ((const float2*)W2)[i];
        w20s[i] = w.x;
        w21s[i] = w.y;
    }
    const int lane = tid & 63;
    const int wv   = tid >> 6;
    const int n    = (blockIdx.x << 2) + wv;
    const float b20 = b2[0];
    const float b21 = b2[1];
    const float xv = x[n * DS + lane];
    float4 a[16];
    const float4* b1v = (const float4*)b1;
    #pragma unroll
    for (int q = 0; q < 16; ++q) a[q] = b1v[q * 64 + lane];
    __syncthreads();
    const float4* w20v = (const float4*)w20s;
    const float4* w21v = (const float4*)w21s;
    float wav = 1.0f;
    for (int d = 0; d < DS; ++d) {
        const float xd = __shfl(xv, d, 64);
        const float4* w1v = (const float4*)(W1 + d * HD);
        float dot0 = 0.0f, dot1 = 0.0f;
        #pragma unroll
        for (int q = 0; q < 16; ++q) {
            float4 w1 = w1v[q * 64 + lane];
            float4 av = a[q];
            float h0 = fast_tanh(av.x);
            float h1 = fast_tanh(av.y);
            float h2 = fast_tanh(av.z);
            float h3 = fast_tanh(av.w);
            float4 c0 = w20v[q * 64 + lane];
            float4 c1 = w21v[q * 64 + lane];
            dot0 = fmaf(h0, c0.x, dot0); dot0 = fmaf(h1, c0.y, dot0);
            dot0 = fmaf(h2, c0.z, dot0); dot0 = fmaf(h3, c0.w, dot0);
            dot1 = fmaf(h0, c1.x, dot1); dot1 = fmaf(h1, c1.y, dot1);
            dot1 = fmaf(h2, c1.z, dot1); dot1 = fmaf(h3, c1.w, dot1);
            av.x = fmaf(xd, w1.x, av.x); av.y = fmaf(xd, w1.y, av.y);
            av.z = fmaf(xd, w1.z, av.z); av.w = fmaf(xd, w1.w, av.w);
            a[q] = av;
        }
        #pragma unroll
        for (int m = 1; m < 64; m <<= 1) {
            dot0 += __shfl_xor(dot0, m, 64);
            dot1 += __shfl_xor(dot1, m, 64);
        }
        float o0 = fast_tanh(dot0 + b20);
        float o1 = fast_tanh(dot1 + b21);
        float nrm = sqrtf(fmaf(o0, o0, o1 * o1));
        nrm = fmaxf(nrm, 1e-12f);
        float sel = (xd > 0.0f) ? o0 : o1;
        wav *= sel / nrm;
    }
    out[n] = wav;
}

extern "C" void kernel_launch(void* const* d_in, const int* in_sizes, int n_in,
                              void* d_out, int out_size, void* d_ws, size_t ws_size,
                              hipStream_t stream) {
    const float* x  = (const float*)d_in[0];
    const float* W1 = (const float*)d_in[1];
    const float* b1 = (const float*)d_in[2];
    const float* W2 = (const float*)d_in[3];
    const float* b2 = (const float*)d_in[4];
    float* out = (float*)d_out;

    const size_t need = (size_t)(2 * DS * HD + 2) * sizeof(float);
    if (ws_size >= need) {
        float* Ep  = (float*)d_ws;
        float* Em  = Ep + DS * HD;
        float* C01 = Em + DS * HD;
        hipLaunchKernelGGL(qnade_prep_E, dim3(DS * HD / 256), dim3(256), 0, stream, W1, Ep, Em);
        hipLaunchKernelGGL(qnade_prep_S, dim3(1), dim3(256), 0, stream, W2, b2, C01);
        hipLaunchKernelGGL(qnade_main, dim3(NS), dim3(256), 0, stream, x, b1, W2, Ep, Em, C01, out);
    } else {
        hipLaunchKernelGGL(qnade_fallback, dim3(NS / 4), dim3(256), 0, stream, x, W1, b1, W2, b2, out);
    }
}